// Round 9
// baseline (165.581 us; speedup 1.0000x reference)
//
#include <hip/hip_runtime.h>

// Affine-IFS scan, decomposed v3 — MEASUREMENT ROUND: kernel launched TWICE
// (idempotent) so dur_us = overhead + 2*K, isolating kernel time K from the
// ~110us harness overhead that hides it (rocprof top-5 shows only 60us
// poison-fills; our dispatch is <59us and invisible). K = dur_us - 140.

#define B_PTS 16384
#define T_STEPS 512
#define N_TR 16
#define PTS_PER_BLK 64
#define WAVES 8
#define L_CHUNK 64   // T_STEPS / WAVES
#define THREADS 512
#define NPAIR 256

__global__ __launch_bounds__(THREADS, 4)
void ifs_scan_v3(const float* __restrict__ init_pts,
                 const float* __restrict__ weights,
                 const float* __restrict__ biases,
                 const float* __restrict__ opac,
                 const int*   __restrict__ code,
                 float*       __restrict__ out)
{
    __shared__ float4 tabA[N_TR];
    __shared__ float4 tabB[N_TR];
    __shared__ float4 pairA[NPAIR];
    __shared__ float2 pairB[NPAIR];
    __shared__ float4 mapsA[WAVES][PTS_PER_BLK];
    __shared__ float2 mapsB[WAVES][PTS_PER_BLK];

    const int tid  = threadIdx.x;
    const int lane = tid & 63;
    const int wv   = tid >> 6;
    const int base = blockIdx.x * PTS_PER_BLK;
    const int b    = base + lane;
    const int t0   = wv * L_CHUNK;

    // ---- load this wave's 64 chunk codes, pack 8 nibbles/dword ----
    unsigned nib[8];
    #pragma unroll
    for (int j = 0; j < 8; ++j) {
        unsigned acc = 0;
        #pragma unroll
        for (int k = 0; k < 8; ++k)
            acc |= (unsigned)code[(size_t)(t0 + 8*j + k) * B_PTS + b] << (4*k);
        nib[j] = acc;
    }

    // ---- build tables ----
    if (tid < N_TR) {
        tabA[tid] = make_float4(weights[tid*4+0], weights[tid*4+1],
                                weights[tid*4+2], weights[tid*4+3]);
        tabB[tid] = make_float4(biases[tid*2+0], biases[tid*2+1], opac[tid], 0.f);
    }
    if (tid >= 64 && tid < 64 + NPAIR) {
        const int n = tid - 64;
        const int i = n & 15, j = n >> 4;         // apply i then j
        const float ai = weights[i*4+0], bi = weights[i*4+1];
        const float ci = weights[i*4+2], di = weights[i*4+3];
        const float aj = weights[j*4+0], bj = weights[j*4+1];
        const float cj = weights[j*4+2], dj = weights[j*4+3];
        const float bxi = biases[i*2+0], byi = biases[i*2+1];
        const float bxj = biases[j*2+0], byj = biases[j*2+1];
        pairA[n] = make_float4(aj*ai + bj*ci, aj*bi + bj*di,
                               cj*ai + dj*ci, cj*bi + dj*di);
        pairB[n] = make_float2(aj*bxi + bj*byi + bxj,
                               cj*bxi + dj*byi + byj);
    }
    __syncthreads();

    // ---- compose chunk map: 32 pair-steps ----
    float m00 = 1.f, m01 = 0.f, m10 = 0.f, m11 = 1.f, vx = 0.f, vy = 0.f;
    #pragma unroll
    for (int j = 0; j < 8; ++j) {
        const unsigned w = nib[j];
        #pragma unroll
        for (int kk = 0; kk < 4; ++kk) {
            const int pidx = (w >> (8*kk)) & 255;
            const float4 P = pairA[pidx];
            const float2 V = pairB[pidx];
            const float n00 = P.x * m00 + P.y * m10;
            const float n01 = P.x * m01 + P.y * m11;
            const float n10 = P.z * m00 + P.w * m10;
            const float n11 = P.z * m01 + P.w * m11;
            const float nvx = P.x * vx + P.y * vy + V.x;
            const float nvy = P.z * vx + P.w * vy + V.y;
            m00 = n00; m01 = n01; m10 = n10; m11 = n11; vx = nvx; vy = nvy;
        }
    }
    mapsA[wv][lane] = make_float4(m00, m01, m10, m11);
    mapsB[wv][lane] = make_float2(vx, vy);
    __syncthreads();

    // ---- prefix ----
    const float2 p0 = *reinterpret_cast<const float2*>(&init_pts[(size_t)b * 2]);
    float px = p0.x, py = p0.y;
    for (int q = 0; q < wv; ++q) {
        const float4 M = mapsA[q][lane];
        const float2 V = mapsB[q][lane];
        const float nx = M.x * px + M.y * py + V.x;
        const float ny = M.z * px + M.w * py + V.y;
        px = nx; py = ny;
    }

    // ---- replay + store ----
    float* op = out + (size_t)((size_t)t0 * B_PTS + b) * 3;
    #pragma unroll
    for (int j = 0; j < 8; ++j) {
        const unsigned w = nib[j];
        #pragma unroll
        for (int k = 0; k < 8; ++k) {
            const int idx   = (w >> (4*k)) & 15;
            const float4 A  = tabA[idx];
            const float4 Bv = tabB[idx];
            const float nx = fmaf(A.x, px, fmaf(A.y, py, Bv.x));
            const float ny = fmaf(A.z, px, fmaf(A.w, py, Bv.y));
            px = nx; py = ny;
            op[0] = fmaf(px, 0.5f, 0.5f);
            op[1] = fmaf(py, 0.5f, 0.5f);
            op[2] = Bv.z;
            op += (size_t)B_PTS * 3;
        }
    }
}

extern "C" void kernel_launch(void* const* d_in, const int* in_sizes, int n_in,
                              void* d_out, int out_size, void* d_ws, size_t ws_size,
                              hipStream_t stream) {
    const float* init_pts = (const float*)d_in[0];
    const float* weights  = (const float*)d_in[1];
    const float* biases   = (const float*)d_in[2];
    const float* opac     = (const float*)d_in[3];
    const int*   code     = (const int*)d_in[4];
    float*       out      = (float*)d_out;

    // Launched twice deliberately: idempotent, isolates kernel time K via
    // dur_us = overhead + 2K. See round journal.
    ifs_scan_v3<<<B_PTS / PTS_PER_BLK, THREADS, 0, stream>>>(
        init_pts, weights, biases, opac, code, out);
    ifs_scan_v3<<<B_PTS / PTS_PER_BLK, THREADS, 0, stream>>>(
        init_pts, weights, biases, opac, code, out);
}

// Round 10
// 137.079 us; speedup vs baseline: 1.2079x; 1.2079x over previous
//
#include <hip/hip_runtime.h>

// Affine-IFS scan, decomposed v4: 512 blocks x 512 thr, 32 points/block,
// half-wave chunks (each 32-lane half owns one 32-step chunk; 16 chunks = T).
// Purpose: 2 blocks/CU (R8 arithmetic kept it at 1) so one block's code-read
// lead-in overlaps the other's store-heavy replay. R9 double-launch measured
// K=25.3us vs 20.4us HBM floor; this targets the ~5us phase-serialization gap.

#define B_PTS 16384
#define T_STEPS 512
#define N_TR 16
#define PTS_PER_BLK 32
#define THREADS 512
#define NCHUNK 16
#define L_CHUNK 32    // T_STEPS / NCHUNK
#define NPAIR 256

__global__ __launch_bounds__(THREADS, 4)
void ifs_scan_v4(const float* __restrict__ init_pts,
                 const float* __restrict__ weights,
                 const float* __restrict__ biases,
                 const float* __restrict__ opac,
                 const int*   __restrict__ code,
                 float*       __restrict__ out)
{
    __shared__ float4 tabA[N_TR];
    __shared__ float4 tabB[N_TR];
    __shared__ float4 pairA[NPAIR];
    __shared__ float2 pairB[NPAIR];
    __shared__ float4 mapsA[NCHUNK][PTS_PER_BLK];   // 8 KB
    __shared__ float2 mapsB[NCHUNK][PTS_PER_BLK];   // 4 KB
    // LDS total ~18.8 KB -> 2 blocks/CU

    const int tid  = threadIdx.x;
    const int lane = tid & 63;
    const int pt   = lane & 31;
    const int half = lane >> 5;
    const int wv   = tid >> 6;
    const int cw   = 2 * wv + half;        // this half-wave's chunk id
    const int base = blockIdx.x * PTS_PER_BLK;
    const int b    = base + pt;
    const int t0   = cw * L_CHUNK;

    // ---- load this chunk's 32 codes, pack 8 nibbles/dword (issue first) ----
    unsigned nib[4];
    #pragma unroll
    for (int j = 0; j < 4; ++j) {
        unsigned acc = 0;
        #pragma unroll
        for (int k = 0; k < 8; ++k)
            acc |= (unsigned)code[(size_t)(t0 + 8*j + k) * B_PTS + b] << (4*k);
        nib[j] = acc;
    }

    // ---- build tables ----
    if (tid < N_TR) {
        tabA[tid] = make_float4(weights[tid*4+0], weights[tid*4+1],
                                weights[tid*4+2], weights[tid*4+3]);
        tabB[tid] = make_float4(biases[tid*2+0], biases[tid*2+1], opac[tid], 0.f);
    }
    if (tid >= 64 && tid < 64 + NPAIR) {
        const int n = tid - 64;
        const int i = n & 15, j = n >> 4;   // apply i then j
        const float ai = weights[i*4+0], bi = weights[i*4+1];
        const float ci = weights[i*4+2], di = weights[i*4+3];
        const float aj = weights[j*4+0], bj = weights[j*4+1];
        const float cj = weights[j*4+2], dj = weights[j*4+3];
        const float bxi = biases[i*2+0], byi = biases[i*2+1];
        const float bxj = biases[j*2+0], byj = biases[j*2+1];
        pairA[n] = make_float4(aj*ai + bj*ci, aj*bi + bj*di,
                               cj*ai + dj*ci, cj*bi + dj*di);
        pairB[n] = make_float2(aj*bxi + bj*byi + bxj,
                               cj*bxi + dj*byi + byj);
    }
    __syncthreads();

    // ---- compose chunk map: 16 pair-steps from packed bytes ----
    float m00 = 1.f, m01 = 0.f, m10 = 0.f, m11 = 1.f, vx = 0.f, vy = 0.f;
    #pragma unroll
    for (int j = 0; j < 4; ++j) {
        const unsigned w = nib[j];
        #pragma unroll
        for (int kk = 0; kk < 4; ++kk) {
            const int pidx = (w >> (8*kk)) & 255;
            const float4 P = pairA[pidx];
            const float2 V = pairB[pidx];
            const float n00 = P.x * m00 + P.y * m10;
            const float n01 = P.x * m01 + P.y * m11;
            const float n10 = P.z * m00 + P.w * m10;
            const float n11 = P.z * m01 + P.w * m11;
            const float nvx = P.x * vx + P.y * vy + V.x;
            const float nvy = P.z * vx + P.w * vy + V.y;
            m00 = n00; m01 = n01; m10 = n10; m11 = n11; vx = nvx; vy = nvy;
        }
    }
    mapsA[cw][pt] = make_float4(m00, m01, m10, m11);   // each lane distinct slot
    mapsB[cw][pt] = make_float2(vx, vy);
    __syncthreads();

    // ---- prefix: apply chunk maps [0..cw) (per-lane bound; halves differ by 1) ----
    const float2 p0 = *reinterpret_cast<const float2*>(&init_pts[(size_t)b * 2]);
    float px = p0.x, py = p0.y;
    for (int q = 0; q < cw; ++q) {
        const float4 M = mapsA[q][pt];     // both halves same addr -> broadcast
        const float2 V = mapsB[q][pt];
        const float nx = M.x * px + M.y * py + V.x;
        const float ny = M.z * px + M.w * py + V.y;
        px = nx; py = ny;
    }

    // ---- replay chunk, write output ----
    float* op = out + (size_t)((size_t)t0 * B_PTS + b) * 3;
    #pragma unroll
    for (int j = 0; j < 4; ++j) {
        const unsigned w = nib[j];
        #pragma unroll
        for (int k = 0; k < 8; ++k) {
            const int idx   = (w >> (4*k)) & 15;
            const float4 A  = tabA[idx];
            const float4 Bv = tabB[idx];
            const float nx = fmaf(A.x, px, fmaf(A.y, py, Bv.x));
            const float ny = fmaf(A.z, px, fmaf(A.w, py, Bv.y));
            px = nx; py = ny;
            op[0] = fmaf(px, 0.5f, 0.5f);
            op[1] = fmaf(py, 0.5f, 0.5f);
            op[2] = Bv.z;
            op += (size_t)B_PTS * 3;
        }
    }
}

extern "C" void kernel_launch(void* const* d_in, const int* in_sizes, int n_in,
                              void* d_out, int out_size, void* d_ws, size_t ws_size,
                              hipStream_t stream) {
    const float* init_pts = (const float*)d_in[0];
    const float* weights  = (const float*)d_in[1];
    const float* biases   = (const float*)d_in[2];
    const float* opac     = (const float*)d_in[3];
    const int*   code     = (const int*)d_in[4];
    float*       out      = (float*)d_out;

    ifs_scan_v4<<<B_PTS / PTS_PER_BLK, THREADS, 0, stream>>>(
        init_pts, weights, biases, opac, code, out);
}